// Round 3
// baseline (8989.079 us; speedup 1.0000x reference)
//
#include <hip/hip_runtime.h>
#include <stdint.h>

// Neural-ODE actor, persistent-block design (R3).
// y' = MLP(y) (96->1024->1024->96), RK4 NSTEP=16 (64 field evals), one kernel.
// Each block owns 64 batch rows; h1 kept in LDS (swizzled); weights pre-packed
// into MFMA B-fragment-linear bf16 so streaming loads are 1KB-coalesced from L2.

#define NSTEP 16

static constexpr int Bsz   = 16384;
static constexpr int IN_D  = 64;
static constexpr int OUT_D = 32;
static constexpr int CMB   = 96;
static constexpr int KP    = 128;
static constexpr int HID   = 1024;

typedef __bf16 bf16x8 __attribute__((ext_vector_type(8)));
typedef float  f32x4  __attribute__((ext_vector_type(4)));

__device__ __forceinline__ uint16_t f2bf(float f) {
  uint32_t u = __float_as_uint(f);
  u += 0x7fffu + ((u >> 16) & 1u);   // RNE; finite inputs
  return (uint16_t)(u >> 16);
}

// ---------------------------------------------------------------------------
// Weight pre-pack: B-fragment-linear. For tile (nt, ks), lane L, elem j:
//   Wf[(nt*ksteps+ks)*512 + L*8 + j] = W[k*ldw + n],  k=ks*32+(L>>4)*8+j,
//   n = nt*16+(L&15); zero-padded outside (Ksrc, Nsrc).
// Matches the verified MFMA B layout (n=lane&15, k=(lane>>4)*8+j).
// ---------------------------------------------------------------------------
__global__ void pack_b(const float* __restrict__ W, uint16_t* __restrict__ Wf,
                       int Ksrc, int Nsrc, int ldw, int ntiles, int ksteps)
{
  int idx = blockIdx.x * 256 + threadIdx.x;
  int total = ntiles * ksteps * 512;
  if (idx >= total) return;
  int j = idx & 7;
  int L = (idx >> 3) & 63;
  int t = idx >> 9;
  int ks = t % ksteps, nt = t / ksteps;
  int k = ks * 32 + ((L >> 4) << 3) + j;
  int n = nt * 16 + (L & 15);
  float v = (k < Ksrc && n < Nsrc) ? W[(size_t)k * ldw + n] : 0.0f;
  Wf[idx] = f2bf(v);
}

// ---------------------------------------------------------------------------
// The whole ODE. Grid: 256 blocks x 256 threads (4 waves), block = 64 rows.
// LDS: h1 [64][1024] bf16 (128 KB) + t [64][128] bf16 (16 KB), XOR-swizzled
// in 16B granules: idx(r,c) = r*ld + ((c>>3) ^ (r&7))*8 + (c&7).
// ---------------------------------------------------------------------------
__global__ __launch_bounds__(256) void ode_kernel(
    const float* __restrict__ x, const float* __restrict__ z,
    const uint16_t* __restrict__ W1f, const float* __restrict__ b1,
    const uint16_t* __restrict__ W2f, const float* __restrict__ b2,
    const uint16_t* __restrict__ W3f, const float* __restrict__ b3,
    const float* __restrict__ lstd, float* __restrict__ out,
    char* strips)
{
  __shared__ uint16_t h1s[64 * 1024];
  __shared__ uint16_t ts [64 * 128];

  const int tid  = threadIdx.x;
  const int wave = tid >> 6;
  const int lane = tid & 63;
  const int q    = lane >> 4;
  const int l16  = lane & 15;
  const int blk  = blockIdx.x;

  char* sb = strips + (size_t)blk * 65536;
  float*    ys   = (float*)sb;                    // y strip    [64][96] f32
  float*    kcs  = (float*)(sb + 24576);          // kacc strip [64][96] f32
  uint16_t* ains = (uint16_t*)(sb + 49152);       // ain strip  [64][128] bf16

  // ---- init strip: y = [x|z], ain = bf16(y) padded ----
  for (int e = tid; e < 64 * 128; e += 256) {
    int r = e >> 7, c = e & 127;
    float v = 0.0f;
    int grow = blk * 64 + r;
    if (c < IN_D)      v = x[(size_t)grow * IN_D + c];
    else if (c < CMB)  v = z[(size_t)grow * OUT_D + (c - IN_D)];
    ains[e] = f2bf(v);
    if (c < CMB) ys[r * CMB + c] = v;
  }
  __syncthreads();

  const float hh = 1.0f / (float)NSTEP;
  const f32x4 z4 = {0.0f, 0.0f, 0.0f, 0.0f};

  for (int it = 0; it < NSTEP * 4; ++it) {
    const int stage = it & 3;

    // ================= phase 1: h1 = relu(ain @ W1 + b1) =================
    // Preload all A-frags (ain strip, global L1/L2-hot): 4 m-tiles x 4 ksteps.
    bf16x8 a1[4][4];
#pragma unroll
    for (int mt = 0; mt < 4; ++mt)
#pragma unroll
      for (int ks = 0; ks < 4; ++ks)
        a1[mt][ks] = *(const bf16x8*)(ains + (mt * 16 + l16) * KP + ks * 32 + q * 8);

    for (int p = 0; p < 4; ++p) {            // 4 n-chunk passes per wave
      f32x4 acc[4][4];
#pragma unroll
      for (int i = 0; i < 4; ++i)
#pragma unroll
        for (int jv = 0; jv < 4; ++jv) acc[i][jv] = z4;

#pragma unroll
      for (int ks = 0; ks < 4; ++ks) {
        bf16x8 bfr[4];
#pragma unroll
        for (int nn = 0; nn < 4; ++nn) {
          int nt = wave * 16 + p * 4 + nn;
          bfr[nn] = *(const bf16x8*)(W1f + ((size_t)nt * 4 + ks) * 512 + lane * 8);
        }
#pragma unroll
        for (int mt = 0; mt < 4; ++mt)
#pragma unroll
          for (int nn = 0; nn < 4; ++nn)
            acc[mt][nn] = __builtin_amdgcn_mfma_f32_16x16x32_bf16(a1[mt][ks], bfr[nn], acc[mt][nn], 0, 0, 0);
      }
      // epilogue -> h1s (swizzled)
#pragma unroll
      for (int nn = 0; nn < 4; ++nn) {
        int ccol = (wave * 16 + p * 4 + nn) * 16 + l16;
        float bv = b1[ccol];
        int cb = ccol >> 3, cl = ccol & 7;
#pragma unroll
        for (int mt = 0; mt < 4; ++mt)
#pragma unroll
          for (int r = 0; r < 4; ++r) {
            int rr = mt * 16 + q * 4 + r;
            float v = fmaxf(acc[mt][nn][r] + bv, 0.0f);
            h1s[rr * 1024 + ((cb ^ (rr & 7)) << 3) + cl] = f2bf(v);
          }
      }
    }
    __syncthreads();

    // ====== phase 2+3: k = (relu(h1 @ W2 + b2)) @ W3 + b3, j-chunked ======
    f32x4 kac[2][4];                         // kacc accum [n-tile][m-tile]
#pragma unroll
    for (int nb = 0; nb < 2; ++nb)
#pragma unroll
      for (int mt = 0; mt < 4; ++mt) kac[nb][mt] = z4;

    for (int jj = 0; jj < 4; ++jj) {
      // phase 2: two j-chunks (j0=2jj, j1=2jj+1) accumulated in one K-pass
      f32x4 p2[2][4][2];
#pragma unroll
      for (int jp = 0; jp < 2; ++jp)
#pragma unroll
        for (int mt = 0; mt < 4; ++mt)
#pragma unroll
          for (int nb = 0; nb < 2; ++nb) p2[jp][mt][nb] = z4;

#pragma unroll 4
      for (int ks = 0; ks < 32; ++ks) {
        bf16x8 af[4];
#pragma unroll
        for (int mt = 0; mt < 4; ++mt) {
          int m = mt * 16 + l16;
          int kb = ks * 4 + q;
          af[mt] = *(const bf16x8*)(h1s + m * 1024 + ((kb ^ (m & 7)) << 3));
        }
        bf16x8 bfr[2][2];
#pragma unroll
        for (int jp = 0; jp < 2; ++jp)
#pragma unroll
          for (int nb = 0; nb < 2; ++nb) {
            int nt = (jj * 2 + jp) * 8 + wave * 2 + nb;
            bfr[jp][nb] = *(const bf16x8*)(W2f + ((size_t)nt * 32 + ks) * 512 + lane * 8);
          }
#pragma unroll
        for (int jp = 0; jp < 2; ++jp)
#pragma unroll
          for (int nb = 0; nb < 2; ++nb)
#pragma unroll
            for (int mt = 0; mt < 4; ++mt)
              p2[jp][mt][nb] = __builtin_amdgcn_mfma_f32_16x16x32_bf16(af[mt], bfr[jp][nb], p2[jp][mt][nb], 0, 0, 0);
      }

      // for each of the two j-chunks: epilogue -> t (LDS), then phase 3
#pragma unroll
      for (int jp = 0; jp < 2; ++jp) {
        const int j = jj * 2 + jp;
        // epilogue: relu + b2 -> ts (swizzled)
#pragma unroll
        for (int nb = 0; nb < 2; ++nb) {
          int cloc = (wave * 2 + nb) * 16 + l16;       // 0..127 within chunk
          float bv = b2[j * 128 + cloc];
          int cb = cloc >> 3, cl = cloc & 7;
#pragma unroll
          for (int mt = 0; mt < 4; ++mt)
#pragma unroll
            for (int r = 0; r < 4; ++r) {
              int rr = mt * 16 + q * 4 + r;
              float v = fmaxf(p2[jp][mt][nb][r] + bv, 0.0f);
              ts[rr * 128 + ((cb ^ (rr & 7)) << 3) + cl] = f2bf(v);
            }
        }
        __syncthreads();
        // phase 3: kac += t @ W3chunk
#pragma unroll
        for (int kk = 0; kk < 4; ++kk) {
          bf16x8 tf[4];
#pragma unroll
          for (int mt = 0; mt < 4; ++mt) {
            int m = mt * 16 + l16;
            int kb = kk * 4 + q;
            tf[mt] = *(const bf16x8*)(ts + m * 128 + ((kb ^ (m & 7)) << 3));
          }
#pragma unroll
          for (int nb = 0; nb < 2; ++nb) {
            int nt3 = wave * 2 + nb;
            int ks3 = j * 4 + kk;
            bf16x8 b3f = *(const bf16x8*)(W3f + ((size_t)nt3 * 32 + ks3) * 512 + lane * 8);
#pragma unroll
            for (int mt = 0; mt < 4; ++mt)
              kac[nb][mt] = __builtin_amdgcn_mfma_f32_16x16x32_bf16(tf[mt], b3f, kac[nb][mt], 0, 0, 0);
          }
        }
        __syncthreads();
      }
    }

    // ================== RK combine (strips, block-private) ==================
    float wk, cc;
    if      (stage == 0) { wk = hh / 6.0f; cc = hh / 2.0f; }
    else if (stage == 1) { wk = hh / 3.0f; cc = hh / 2.0f; }
    else if (stage == 2) { wk = hh / 3.0f; cc = hh; }
    else                 { wk = hh / 6.0f; cc = 0.0f; }

#pragma unroll
    for (int nb = 0; nb < 2; ++nb) {
      int c = (wave * 2 + nb) * 16 + l16;
      if (c < CMB) {
        float bv = b3[c];
#pragma unroll
        for (int mt = 0; mt < 4; ++mt)
#pragma unroll
          for (int r = 0; r < 4; ++r) {
            int row = mt * 16 + q * 4 + r;
            float kv = kac[nb][mt][r] + bv;
            int yi = row * CMB + c;
            float av;
            if (stage == 3) {
              float yn = ys[yi] + kcs[yi] + wk * kv;
              ys[yi] = yn;
              av = yn;
            } else {
              float ka = (stage == 0) ? (wk * kv) : (kcs[yi] + wk * kv);
              kcs[yi] = ka;
              av = ys[yi] + cc * kv;
            }
            ains[row * KP + c] = f2bf(av);
          }
      }
    }
    __syncthreads();
  }

  // ---------------- output: action = y[:,64:96], std = exp(log_std) --------
  for (int e = tid; e < 64 * 32; e += 256) {
    int r = e >> 5, c = e & 31;
    int grow = blk * 64 + r;
    out[(size_t)grow * OUT_D + c] = ys[r * CMB + IN_D + c];
    out[(size_t)Bsz * OUT_D + (size_t)grow * OUT_D + c] = expf(lstd[c]);
  }
}

extern "C" void kernel_launch(void* const* d_in, const int* in_sizes, int n_in,
                              void* d_out, int out_size, void* d_ws, size_t ws_size,
                              hipStream_t stream) {
  const float* x    = (const float*)d_in[0];
  const float* z    = (const float*)d_in[1];
  const float* W1   = (const float*)d_in[2];
  const float* b1   = (const float*)d_in[3];
  const float* W2   = (const float*)d_in[4];
  const float* b2   = (const float*)d_in[5];
  const float* W3   = (const float*)d_in[6];
  const float* b3   = (const float*)d_in[7];
  const float* lstd = (const float*)d_in[8];
  float* out = (float*)d_out;
  (void)in_sizes; (void)n_in; (void)out_size; (void)ws_size;

  char* p = (char*)d_ws;
  auto alloc = [&](size_t bytes) {
    char* r = p;
    p += (bytes + 255) & ~(size_t)255;
    return r;
  };
  uint16_t* W1f = (uint16_t*)alloc((size_t)64 * 4  * 512 * 2);   // 256 KB
  uint16_t* W2f = (uint16_t*)alloc((size_t)64 * 32 * 512 * 2);   // 2 MB
  uint16_t* W3f = (uint16_t*)alloc((size_t)8  * 32 * 512 * 2);   // 256 KB
  char*     strips = alloc((size_t)256 * 65536);                 // 16 MB

  pack_b<<<(64 * 4  * 512 + 255) / 256, 256, 0, stream>>>(W1, W1f, CMB, HID, HID, 64, 4);
  pack_b<<<(64 * 32 * 512 + 255) / 256, 256, 0, stream>>>(W2, W2f, HID, HID, HID, 64, 32);
  pack_b<<<(8  * 32 * 512 + 255) / 256, 256, 0, stream>>>(W3, W3f, HID, CMB, CMB, 8, 32);

  ode_kernel<<<256, 256, 0, stream>>>(x, z, W1f, b1, W2f, b2, W3f, b3, lstd, out, strips);
}

// Round 4
// 6361.293 us; speedup vs baseline: 1.4131x; 1.4131x over previous
//
#include <hip/hip_runtime.h>
#include <stdint.h>

// Neural-ODE actor, persistent-block design v2 (R4).
// Operand-swapped MFMAs: weights = A operand (pre-packed fragment-linear in
// global, 1KB coalesced L2-hot loads), activations = B operand (contiguous
// ds_read_b128 from swizzled LDS). Phase-3 (h2 @ W3) consumes phase-2 output
// directly from registers via a shuffle transpose; per-wave partial k-vectors
// are reduced through a bf16 LDS slot buffer aliased onto h1s.
// 8 waves/block, LDS 147456 B -> 1 block/CU, 2 waves/SIMD.

#define NSTEP 16

static constexpr int Bsz   = 16384;
static constexpr int IN_D  = 64;
static constexpr int OUT_D = 32;
static constexpr int CMB   = 96;
static constexpr int KP    = 128;
static constexpr int HID   = 1024;

typedef __bf16 bf16x8 __attribute__((ext_vector_type(8)));
typedef float  f32x4  __attribute__((ext_vector_type(4)));

__device__ __forceinline__ uint16_t f2bf(float f) {
  uint32_t u = __float_as_uint(f);
  u += 0x7fffu + ((u >> 16) & 1u);   // RNE; finite inputs
  return (uint16_t)(u >> 16);
}
__device__ __forceinline__ uint32_t pk2(float a, float b) {
  return (uint32_t)f2bf(a) | ((uint32_t)f2bf(b) << 16);
}

// ---------------------------------------------------------------------------
// Weight pack, MFMA A-fragment-linear: Wf[(tile_m*ksteps+ks)*512 + L*8 + j]
//  = src(k, m), m = tile_m*16 + (L&15), k = ks*32 + (L>>4)*8 + j.
//  src = W[k*ldw+m] for k<Ksrc; bias[m] at k==Ksrc (b1 fold); else 0.
// ---------------------------------------------------------------------------
__global__ void pack_w(const float* __restrict__ W, const float* __restrict__ bias,
                       uint16_t* __restrict__ Wf, int Ksrc, int ldw, int ksteps, int total)
{
  int idx = blockIdx.x * 256 + threadIdx.x;
  if (idx >= total) return;
  int j = idx & 7;
  int L = (idx >> 3) & 63;
  int t = idx >> 9;
  int ks = t % ksteps, tm = t / ksteps;
  int k = ks * 32 + ((L >> 4) << 3) + j;
  int m = tm * 16 + (L & 15);
  float v;
  if (k < Ksrc)            v = W[(size_t)k * ldw + m];
  else if (k == Ksrc && bias) v = bias[m];
  else                     v = 0.0f;
  Wf[idx] = f2bf(v);
}

// ---------------------------------------------------------------------------
// Persistent ODE kernel. 256 blocks x 512 threads (8 waves), block = 64 rows.
// LDS: h1s [64][1024] bf16 swizzled (128 KB; aliased as [8][64][128] bf16
//      reduction slots after phase-2), ains [64][128] bf16 swizzled (16 KB).
// Swizzle (8-elem granules): idx(r,c) = r*ld + ((c>>3)^(r&7))*8 + (c&7).
// ---------------------------------------------------------------------------
__global__ __launch_bounds__(512, 2) void ode_kernel(
    const float* __restrict__ x, const float* __restrict__ z,
    const uint16_t* __restrict__ W1f, const uint16_t* __restrict__ W2f,
    const uint16_t* __restrict__ W3f,
    const float* __restrict__ b2, const float* __restrict__ b3,
    const float* __restrict__ lstd, float* __restrict__ out,
    char* __restrict__ strips)
{
  __shared__ uint16_t h1s [64 * 1024];   // also reused as slots[8][64][128]
  __shared__ uint16_t ains[64 * 128];

  const int tid  = threadIdx.x;
  const int wave = tid >> 6;
  const int lane = tid & 63;
  const int q    = lane >> 4;
  const int l16  = lane & 15;
  const int blk  = blockIdx.x;

  float* ys  = (float*)(strips + (size_t)blk * 49152);         // [64][96] f32
  float* kcs = (float*)(strips + (size_t)blk * 49152 + 24576); // [64][96] f32

  // ---- init: ains = bf16([x|z, 1.0, 0...]) swizzled; ys = [x|z] ----
  for (int e = tid; e < 64 * 128; e += 512) {
    int n = e >> 7, c = e & 127;
    int grow = blk * 64 + n;
    float v;
    if (c < IN_D)      v = x[(size_t)grow * IN_D + c];
    else if (c < CMB)  v = z[(size_t)grow * OUT_D + (c - IN_D)];
    else if (c == CMB) v = 1.0f;                   // bias-fold column for W1
    else               v = 0.0f;
    ains[n * 128 + (((c >> 3) ^ (n & 7)) << 3) + (c & 7)] = f2bf(v);
    if (c < CMB) ys[n * CMB + c] = v;
  }
  __syncthreads();

  const float hh = 1.0f / (float)NSTEP;
  const f32x4 z4 = {0.0f, 0.0f, 0.0f, 0.0f};

  for (int it = 0; it < NSTEP * 4; ++it) {
    const int stage = it & 3;

    // ================= phase 1: h1 = relu(W1^T @ ain^T) ====================
    // A = W1f (m=hid1), B = ains (n=batch). b1 folded via ain col 96 = 1.
#pragma unroll
    for (int pass = 0; pass < 2; ++pass) {
      const int mtb = wave * 8 + pass * 4;
      f32x4 acc[4][4];
#pragma unroll
      for (int i = 0; i < 4; ++i)
#pragma unroll
        for (int n = 0; n < 4; ++n) acc[i][n] = z4;

#pragma unroll
      for (int ks = 0; ks < 4; ++ks) {
        bf16x8 af[4], bfr[4];
#pragma unroll
        for (int mi = 0; mi < 4; ++mi)
          af[mi] = *(const bf16x8*)(W1f + ((size_t)(mtb + mi) * 4 + ks) * 512 + lane * 8);
#pragma unroll
        for (int nt = 0; nt < 4; ++nt) {
          int bn = nt * 16 + l16;
          bfr[nt] = *(const bf16x8*)(ains + bn * 128 + ((((ks * 4 + q)) ^ (bn & 7)) << 3));
        }
#pragma unroll
        for (int mi = 0; mi < 4; ++mi)
#pragma unroll
          for (int nt = 0; nt < 4; ++nt)
            acc[mi][nt] = __builtin_amdgcn_mfma_f32_16x16x32_bf16(af[mi], bfr[nt], acc[mi][nt], 0, 0, 0);
      }
      // epilogue: relu -> h1s, b64 quad per (mi, nt)
#pragma unroll
      for (int mi = 0; mi < 4; ++mi) {
        const int m0 = (mtb + mi) * 16 + q * 4;   // 4 consecutive hid1
#pragma unroll
        for (int nt = 0; nt < 4; ++nt) {
          const int bn = nt * 16 + l16;
          uint64_t pk = (uint64_t)pk2(fmaxf(acc[mi][nt][0], 0.0f), fmaxf(acc[mi][nt][1], 0.0f))
                      | ((uint64_t)pk2(fmaxf(acc[mi][nt][2], 0.0f), fmaxf(acc[mi][nt][3], 0.0f)) << 32);
          *(uint64_t*)(h1s + bn * 1024 + (((m0 >> 3) ^ (bn & 7)) << 3) + (m0 & 4)) = pk;
        }
      }
    }
    __syncthreads();

    // ====== phase 2+3: k = relu(W2^T @ h1^T + b2) fed straight into W3 =====
    f32x4 kac[6][4];
#pragma unroll
    for (int m3 = 0; m3 < 6; ++m3)
#pragma unroll
      for (int nt = 0; nt < 4; ++nt) kac[m3][nt] = z4;

#pragma unroll
    for (int pass = 0; pass < 2; ++pass) {
      const int mtb2 = wave * 8 + pass * 4;       // hid2 tile base (16-wide)
      f32x4 acc[4][4];
#pragma unroll
      for (int i = 0; i < 4; ++i)
#pragma unroll
        for (int n = 0; n < 4; ++n) acc[i][n] = z4;

#pragma unroll 4
      for (int ks = 0; ks < 32; ++ks) {
        bf16x8 af[4], bfr[4];
#pragma unroll
        for (int mi = 0; mi < 4; ++mi)
          af[mi] = *(const bf16x8*)(W2f + ((size_t)(mtb2 + mi) * 32 + ks) * 512 + lane * 8);
#pragma unroll
        for (int nt = 0; nt < 4; ++nt) {
          int bn = nt * 16 + l16;
          bfr[nt] = *(const bf16x8*)(h1s + bn * 1024 + ((((ks * 4 + q)) ^ (bn & 7)) << 3));
        }
#pragma unroll
        for (int mi = 0; mi < 4; ++mi)
#pragma unroll
          for (int nt = 0; nt < 4; ++nt)
            acc[mi][nt] = __builtin_amdgcn_mfma_f32_16x16x32_bf16(af[mi], bfr[nt], acc[mi][nt], 0, 0, 0);
      }

      // bias + relu + in-register transpose -> phase-3 B fragments.
      // D layout: col(batch)=l16, row(hid2-local)=q*4+r. B-frag wants
      // k=q*8+j: j0-3 <- lane l16+32*(q&1), j4-7 <- +16, tile = q>>1.
#pragma unroll
      for (int kt = 0; kt < 2; ++kt) {            // 32-wide hid2 k-tiles
        float bv0[4], bv1[4];
#pragma unroll
        for (int r = 0; r < 4; ++r) {
          bv0[r] = b2[(mtb2 + 2 * kt)     * 16 + q * 4 + r];
          bv1[r] = b2[(mtb2 + 2 * kt + 1) * 16 + q * 4 + r];
        }
        const int srcA = l16 + 32 * (q & 1);
        const int srcB = srcA + 16;
        const bool sel = (q < 2);

        bf16x8 B3[4];
#pragma unroll
        for (int nt = 0; nt < 4; ++nt) {
          float t00 = fmaxf(acc[2 * kt][nt][0] + bv0[0], 0.0f);
          float t01 = fmaxf(acc[2 * kt][nt][1] + bv0[1], 0.0f);
          float t02 = fmaxf(acc[2 * kt][nt][2] + bv0[2], 0.0f);
          float t03 = fmaxf(acc[2 * kt][nt][3] + bv0[3], 0.0f);
          float t10 = fmaxf(acc[2 * kt + 1][nt][0] + bv1[0], 0.0f);
          float t11 = fmaxf(acc[2 * kt + 1][nt][1] + bv1[1], 0.0f);
          float t12 = fmaxf(acc[2 * kt + 1][nt][2] + bv1[2], 0.0f);
          float t13 = fmaxf(acc[2 * kt + 1][nt][3] + bv1[3], 0.0f);
          uint32_t w00 = pk2(t00, t01), w01 = pk2(t02, t03);
          uint32_t w10 = pk2(t10, t11), w11 = pk2(t12, t13);
          uint32_t a00 = (uint32_t)__shfl((int)w00, srcA, 64);
          uint32_t a01 = (uint32_t)__shfl((int)w01, srcA, 64);
          uint32_t a10 = (uint32_t)__shfl((int)w10, srcA, 64);
          uint32_t a11 = (uint32_t)__shfl((int)w11, srcA, 64);
          uint32_t b00 = (uint32_t)__shfl((int)w00, srcB, 64);
          uint32_t b01 = (uint32_t)__shfl((int)w01, srcB, 64);
          uint32_t b10 = (uint32_t)__shfl((int)w10, srcB, 64);
          uint32_t b11 = (uint32_t)__shfl((int)w11, srcB, 64);
          union { uint32_t u[4]; bf16x8 v; } cvt;
          cvt.u[0] = sel ? a00 : a10;
          cvt.u[1] = sel ? a01 : a11;
          cvt.u[2] = sel ? b00 : b10;
          cvt.u[3] = sel ? b01 : b11;
          B3[nt] = cvt.v;
        }
        // phase 3: kac += W3^T-frag @ B3 over this wave's hid2 k-slice
        const int ks3 = wave * 4 + pass * 2 + kt;
#pragma unroll
        for (int m3 = 0; m3 < 6; ++m3) {
          bf16x8 a3 = *(const bf16x8*)(W3f + ((size_t)m3 * 32 + ks3) * 512 + lane * 8);
#pragma unroll
          for (int nt = 0; nt < 4; ++nt)
            kac[m3][nt] = __builtin_amdgcn_mfma_f32_16x16x32_bf16(a3, B3[nt], kac[m3][nt], 0, 0, 0);
        }
      }
    }
    __syncthreads();   // all h1s reads done; region becomes slot buffer

    // write per-wave bf16 partials: slots[wave][n][m] (swizzled granules)
#pragma unroll
    for (int m3 = 0; m3 < 6; ++m3) {
      const int m0 = m3 * 16 + q * 4;
#pragma unroll
      for (int nt = 0; nt < 4; ++nt) {
        const int bn = nt * 16 + l16;
        uint64_t pk = (uint64_t)pk2(kac[m3][nt][0], kac[m3][nt][1])
                    | ((uint64_t)pk2(kac[m3][nt][2], kac[m3][nt][3]) << 32);
        *(uint64_t*)(h1s + wave * 8192 + bn * 128 + (((m0 >> 3) ^ (bn & 7)) << 3) + (m0 & 4)) = pk;
      }
    }
    __syncthreads();

    // ===================== reduce + RK combine =============================
    float wk, cc;
    if      (stage == 0) { wk = hh / 6.0f; cc = hh / 2.0f; }
    else if (stage == 1) { wk = hh / 3.0f; cc = hh / 2.0f; }
    else if (stage == 2) { wk = hh / 3.0f; cc = hh; }
    else                 { wk = hh / 6.0f; cc = 0.0f; }

#pragma unroll
    for (int rep = 0; rep < 2; ++rep) {
      const int n  = rep * 32 + (tid >> 4);
      const int m0 = (tid & 15) * 8;
      const int gsw = (((m0 >> 3) ^ (n & 7)) << 3);
      if (m0 < CMB) {
        float kt8[8];
#pragma unroll
        for (int e = 0; e < 8; ++e) kt8[e] = b3[m0 + e];
#pragma unroll
        for (int w = 0; w < 8; ++w) {
          bf16x8 v = *(const bf16x8*)(h1s + w * 8192 + n * 128 + gsw);
#pragma unroll
          for (int e = 0; e < 8; ++e) kt8[e] += (float)v[e];
        }
        uint16_t av[8];
#pragma unroll
        for (int e = 0; e < 8; ++e) {
          const int yi = n * CMB + m0 + e;
          float kv = kt8[e];
          float a;
          if (stage == 3) {
            float yn = ys[yi] + kcs[yi] + wk * kv;
            ys[yi] = yn;
            a = yn;
          } else {
            float ka = (stage == 0) ? (wk * kv) : (kcs[yi] + wk * kv);
            kcs[yi] = ka;
            a = ys[yi] + cc * kv;
          }
          av[e] = f2bf(a);
        }
        *(uint64_t*)(ains + n * 128 + gsw)     = *(const uint64_t*)&av[0];
        *(uint64_t*)(ains + n * 128 + gsw + 4) = *(const uint64_t*)&av[4];
      } else {
        // constant pad columns: 96 -> 1.0 (bias fold), 97..127 -> 0
        uint16_t av[8];
#pragma unroll
        for (int e = 0; e < 8; ++e) av[e] = (m0 + e == CMB) ? (uint16_t)0x3F80 : (uint16_t)0;
        *(uint64_t*)(ains + n * 128 + gsw)     = *(const uint64_t*)&av[0];
        *(uint64_t*)(ains + n * 128 + gsw + 4) = *(const uint64_t*)&av[4];
      }
    }
    __syncthreads();
  }

  // ---------------- output: action = y[:,64:96], std = exp(log_std) --------
  for (int e = tid; e < 64 * 32; e += 512) {
    int n = e >> 5, c = e & 31;
    int grow = blk * 64 + n;
    out[(size_t)grow * OUT_D + c] = ys[n * CMB + IN_D + c];
    out[(size_t)Bsz * OUT_D + (size_t)grow * OUT_D + c] = expf(lstd[c]);
  }
}

extern "C" void kernel_launch(void* const* d_in, const int* in_sizes, int n_in,
                              void* d_out, int out_size, void* d_ws, size_t ws_size,
                              hipStream_t stream) {
  const float* x    = (const float*)d_in[0];
  const float* z    = (const float*)d_in[1];
  const float* W1   = (const float*)d_in[2];
  const float* b1   = (const float*)d_in[3];
  const float* W2   = (const float*)d_in[4];
  const float* b2   = (const float*)d_in[5];
  const float* W3   = (const float*)d_in[6];
  const float* b3   = (const float*)d_in[7];
  const float* lstd = (const float*)d_in[8];
  float* out = (float*)d_out;
  (void)in_sizes; (void)n_in; (void)out_size; (void)ws_size;

  char* p = (char*)d_ws;
  auto alloc = [&](size_t bytes) {
    char* r = p;
    p += (bytes + 255) & ~(size_t)255;
    return r;
  };
  uint16_t* W1f = (uint16_t*)alloc((size_t)64 * 4  * 512 * 2);  // 256 KB
  uint16_t* W2f = (uint16_t*)alloc((size_t)64 * 32 * 512 * 2);  // 2 MB
  uint16_t* W3f = (uint16_t*)alloc((size_t)6  * 32 * 512 * 2);  // 192 KB
  char*     strips = alloc((size_t)256 * 49152);                // 12 MB

  // W1: m=hid1, k over padded CMB(128); b1 folded at k==96. W2: plain k<1024.
  // W3: m=out(96, 6 tiles), k=hid2.
  {
    int tot1 = 64 * 4 * 512;
    pack_w<<<(tot1 + 255) / 256, 256, 0, stream>>>(W1, b1, W1f, CMB, HID, 4, tot1);
    int tot2 = 64 * 32 * 512;
    pack_w<<<(tot2 + 255) / 256, 256, 0, stream>>>(W2, nullptr, W2f, HID, HID, 32, tot2);
    int tot3 = 6 * 32 * 512;
    pack_w<<<(tot3 + 255) / 256, 256, 0, stream>>>(W3, nullptr, W3f, HID, CMB, 32, tot3);
  }

  ode_kernel<<<256, 512, 0, stream>>>(x, z, W1f, W2f, W3f, b2, b3, lstd, out, strips);
}

// Round 5
// 4625.107 us; speedup vs baseline: 1.9435x; 1.3754x over previous
//
#include <hip/hip_runtime.h>
#include <stdint.h>

// Neural-ODE actor, persistent-block design v3 (R5).
// R4 + : (1) nontemporal ys/kcs strip access (keep L2 for weights),
//        (2) register double-buffered weight prefetch in phase 2,
//        (3) weight pack re-layout: 4 KB contiguous chunk per (wave,pass,ks),
//            W3 ks-major. 8 waves/block, LDS 147456 B, 2 waves/SIMD.

#define NSTEP 16

static constexpr int Bsz   = 16384;
static constexpr int IN_D  = 64;
static constexpr int OUT_D = 32;
static constexpr int CMB   = 96;
static constexpr int KP    = 128;
static constexpr int HID   = 1024;

typedef __bf16 bf16x8 __attribute__((ext_vector_type(8)));
typedef float  f32x4  __attribute__((ext_vector_type(4)));

__device__ __forceinline__ uint16_t f2bf(float f) {
  uint32_t u = __float_as_uint(f);
  u += 0x7fffu + ((u >> 16) & 1u);   // RNE; finite inputs
  return (uint16_t)(u >> 16);
}
__device__ __forceinline__ uint32_t pk2(float a, float b) {
  return (uint32_t)f2bf(a) | ((uint32_t)f2bf(b) << 16);
}

// ---------------------------------------------------------------------------
// Weight pack. Fragment = 512 bf16 (lane*8+j), A-layout: m=tile*16+(L&15),
// k=ks*32+(L>>4)*8+j. Output tile order:
//   mode 0 (grouped-4): out_t = ((tm>>2)*ksteps + ks)*4 + (tm&3)
//   mode 1 (ks-major) : out_t = ks*ntiles + tm
// src = W[k*ldw+m] for k<Ksrc; bias[m] at k==Ksrc (fold); else 0.
// ---------------------------------------------------------------------------
__global__ void pack_w(const float* __restrict__ W, const float* __restrict__ bias,
                       uint16_t* __restrict__ Wf, int Ksrc, int ldw,
                       int ksteps, int ntiles, int mode, int total)
{
  int idx = blockIdx.x * 256 + threadIdx.x;
  if (idx >= total) return;
  int j = idx & 7;
  int L = (idx >> 3) & 63;
  int t = idx >> 9;            // output tile index
  int tm, ks;
  if (mode == 0) {
    int sub = t & 3;
    int q2  = t >> 2;          // g*ksteps + ks
    ks = q2 % ksteps;
    tm = (q2 / ksteps) * 4 + sub;
  } else {
    tm = t % ntiles;
    ks = t / ntiles;
  }
  int k = ks * 32 + ((L >> 4) << 3) + j;
  int m = tm * 16 + (L & 15);
  float v;
  if (k < Ksrc)               v = W[(size_t)k * ldw + m];
  else if (k == Ksrc && bias) v = bias[m];
  else                        v = 0.0f;
  Wf[idx] = f2bf(v);
}

// ---------------------------------------------------------------------------
// Persistent ODE kernel. 256 blocks x 512 threads (8 waves), block = 64 rows.
// LDS: h1s [64][1024] bf16 swizzled (128 KB; aliased as slots[8][64][128]
//      after phase-2), ains [64][128] bf16 swizzled (16 KB).
// Swizzle (8-elem granules): idx(r,c) = r*ld + ((c>>3)^(r&7))*8 + (c&7).
// ---------------------------------------------------------------------------
__global__ __launch_bounds__(512, 2) void ode_kernel(
    const float* __restrict__ x, const float* __restrict__ z,
    const uint16_t* __restrict__ W1f, const uint16_t* __restrict__ W2f,
    const uint16_t* __restrict__ W3f,
    const float* __restrict__ b2, const float* __restrict__ b3,
    const float* __restrict__ lstd, float* __restrict__ out,
    char* __restrict__ strips)
{
  __shared__ uint16_t h1s [64 * 1024];   // reused as slots[8][64][128]
  __shared__ uint16_t ains[64 * 128];

  const int tid  = threadIdx.x;
  const int wave = tid >> 6;
  const int lane = tid & 63;
  const int q    = lane >> 4;
  const int l16  = lane & 15;
  const int blk  = blockIdx.x;

  float* ys  = (float*)(strips + (size_t)blk * 49152);         // [64][96] f32
  float* kcs = (float*)(strips + (size_t)blk * 49152 + 24576); // [64][96] f32

  // ---- init: ains = bf16([x|z, 1.0, 0...]) swizzled; ys = [x|z] (NT) ----
  for (int e = tid; e < 64 * 128; e += 512) {
    int n = e >> 7, c = e & 127;
    int grow = blk * 64 + n;
    float v;
    if (c < IN_D)      v = x[(size_t)grow * IN_D + c];
    else if (c < CMB)  v = z[(size_t)grow * OUT_D + (c - IN_D)];
    else if (c == CMB) v = 1.0f;                   // bias-fold column for W1
    else               v = 0.0f;
    ains[n * 128 + (((c >> 3) ^ (n & 7)) << 3) + (c & 7)] = f2bf(v);
    if (c < CMB) __builtin_nontemporal_store(v, &ys[n * CMB + c]);
  }
  __syncthreads();

  const float hh = 1.0f / (float)NSTEP;
  const f32x4 z4 = {0.0f, 0.0f, 0.0f, 0.0f};

  // fragment loaders (LDS arrays captured by ref -> compiler keeps ds_ ops)
  auto ld_a1 = [&](int ks, bf16x8* bfr) {      // ains B-frags
#pragma unroll
    for (int nt = 0; nt < 4; ++nt) {
      int bn = nt * 16 + l16;
      bfr[nt] = *(const bf16x8*)(ains + bn * 128 + (((ks * 4 + q) ^ (bn & 7)) << 3));
    }
  };
  auto ld_h = [&](int ks, bf16x8* bfr) {       // h1s B-frags
#pragma unroll
    for (int nt = 0; nt < 4; ++nt) {
      int bn = nt * 16 + l16;
      bfr[nt] = *(const bf16x8*)(h1s + bn * 1024 + (((ks * 4 + q) ^ (bn & 7)) << 3));
    }
  };

  for (int it = 0; it < NSTEP * 4; ++it) {
    const int stage = it & 3;

    // ================= phase 1: h1 = relu(W1^T @ ain^T) ====================
#pragma unroll
    for (int pass = 0; pass < 2; ++pass) {
      const int g1 = (wave * 2 + pass);
      auto ld_w1 = [&](int ks, bf16x8* af) {
        const uint16_t* b = W1f + (size_t)((g1 * 4 + ks) * 4) * 512 + lane * 8;
#pragma unroll
        for (int mi = 0; mi < 4; ++mi) af[mi] = *(const bf16x8*)(b + mi * 512);
      };
      f32x4 acc[4][4];
#pragma unroll
      for (int i = 0; i < 4; ++i)
#pragma unroll
        for (int n = 0; n < 4; ++n) acc[i][n] = z4;

      bf16x8 afA[4], afB[4], bf[4];
      auto do16 = [&](bf16x8* af, bf16x8* bfr) {
#pragma unroll
        for (int mi = 0; mi < 4; ++mi)
#pragma unroll
          for (int nt = 0; nt < 4; ++nt)
            acc[mi][nt] = __builtin_amdgcn_mfma_f32_16x16x32_bf16(af[mi], bfr[nt], acc[mi][nt], 0, 0, 0);
      };
      ld_w1(0, afA);
      ld_w1(1, afB); ld_a1(0, bf); do16(afA, bf);
      ld_w1(2, afA); ld_a1(1, bf); do16(afB, bf);
      ld_w1(3, afB); ld_a1(2, bf); do16(afA, bf);
                     ld_a1(3, bf); do16(afB, bf);

      // epilogue: relu -> h1s, b64 quad per (mi, nt)
      const int mtb = wave * 8 + pass * 4;
#pragma unroll
      for (int mi = 0; mi < 4; ++mi) {
        const int m0 = (mtb + mi) * 16 + q * 4;
#pragma unroll
        for (int nt = 0; nt < 4; ++nt) {
          const int bn = nt * 16 + l16;
          uint64_t pk = (uint64_t)pk2(fmaxf(acc[mi][nt][0], 0.0f), fmaxf(acc[mi][nt][1], 0.0f))
                      | ((uint64_t)pk2(fmaxf(acc[mi][nt][2], 0.0f), fmaxf(acc[mi][nt][3], 0.0f)) << 32);
          *(uint64_t*)(h1s + bn * 1024 + (((m0 >> 3) ^ (bn & 7)) << 3) + (m0 & 4)) = pk;
        }
      }
    }
    __syncthreads();

    // ====== phase 2+3: k = relu(W2^T @ h1^T + b2) fed straight into W3 =====
    f32x4 kac[6][4];
#pragma unroll
    for (int m3 = 0; m3 < 6; ++m3)
#pragma unroll
      for (int nt = 0; nt < 4; ++nt) kac[m3][nt] = z4;

#pragma unroll
    for (int pass = 0; pass < 2; ++pass) {
      const int g2 = (wave * 2 + pass);
      auto ld_w2 = [&](int ks, bf16x8* af) {
        const uint16_t* b = W2f + (size_t)((g2 * 32 + ks) * 4) * 512 + lane * 8;
#pragma unroll
        for (int mi = 0; mi < 4; ++mi) af[mi] = *(const bf16x8*)(b + mi * 512);
      };
      f32x4 acc[4][4];
#pragma unroll
      for (int i = 0; i < 4; ++i)
#pragma unroll
        for (int n = 0; n < 4; ++n) acc[i][n] = z4;

      bf16x8 afA[4], afB[4], bf[4];
      auto do16 = [&](bf16x8* af, bf16x8* bfr) {
#pragma unroll
        for (int mi = 0; mi < 4; ++mi)
#pragma unroll
          for (int nt = 0; nt < 4; ++nt)
            acc[mi][nt] = __builtin_amdgcn_mfma_f32_16x16x32_bf16(af[mi], bfr[nt], acc[mi][nt], 0, 0, 0);
      };

      ld_w2(0, afA);
#pragma unroll 2
      for (int ks = 0; ks < 28; ks += 2) {
        ld_w2(ks + 1, afB);
        ld_h(ks, bf);     do16(afA, bf);
        ld_w2(ks + 2, afA);
        ld_h(ks + 1, bf); do16(afB, bf);
      }
      // tail: ks = 28..31 (afA holds ks=28)
      ld_w2(29, afB); ld_h(28, bf); do16(afA, bf);
      ld_w2(30, afA); ld_h(29, bf); do16(afB, bf);
      ld_w2(31, afB); ld_h(30, bf); do16(afA, bf);
                      ld_h(31, bf); do16(afB, bf);

      // bias + relu + in-register transpose -> phase-3 B fragments.
      // D layout: col(batch)=l16, row(hid2-local)=q*4+r. B-frag wants
      // k=q*8+j: j0-3 <- lane l16+32*(q&1), j4-7 <- +16, tile = q>>1.
      const int mtb2 = wave * 8 + pass * 4;
#pragma unroll
      for (int kt = 0; kt < 2; ++kt) {
        float bv0[4], bv1[4];
#pragma unroll
        for (int r = 0; r < 4; ++r) {
          bv0[r] = b2[(mtb2 + 2 * kt)     * 16 + q * 4 + r];
          bv1[r] = b2[(mtb2 + 2 * kt + 1) * 16 + q * 4 + r];
        }
        const int srcA = l16 + 32 * (q & 1);
        const int srcB = srcA + 16;
        const bool sel = (q < 2);

        bf16x8 B3[4];
#pragma unroll
        for (int nt = 0; nt < 4; ++nt) {
          float t00 = fmaxf(acc[2 * kt][nt][0] + bv0[0], 0.0f);
          float t01 = fmaxf(acc[2 * kt][nt][1] + bv0[1], 0.0f);
          float t02 = fmaxf(acc[2 * kt][nt][2] + bv0[2], 0.0f);
          float t03 = fmaxf(acc[2 * kt][nt][3] + bv0[3], 0.0f);
          float t10 = fmaxf(acc[2 * kt + 1][nt][0] + bv1[0], 0.0f);
          float t11 = fmaxf(acc[2 * kt + 1][nt][1] + bv1[1], 0.0f);
          float t12 = fmaxf(acc[2 * kt + 1][nt][2] + bv1[2], 0.0f);
          float t13 = fmaxf(acc[2 * kt + 1][nt][3] + bv1[3], 0.0f);
          uint32_t w00 = pk2(t00, t01), w01 = pk2(t02, t03);
          uint32_t w10 = pk2(t10, t11), w11 = pk2(t12, t13);
          uint32_t a00 = (uint32_t)__shfl((int)w00, srcA, 64);
          uint32_t a01 = (uint32_t)__shfl((int)w01, srcA, 64);
          uint32_t a10 = (uint32_t)__shfl((int)w10, srcA, 64);
          uint32_t a11 = (uint32_t)__shfl((int)w11, srcA, 64);
          uint32_t b00 = (uint32_t)__shfl((int)w00, srcB, 64);
          uint32_t b01 = (uint32_t)__shfl((int)w01, srcB, 64);
          uint32_t b10 = (uint32_t)__shfl((int)w10, srcB, 64);
          uint32_t b11 = (uint32_t)__shfl((int)w11, srcB, 64);
          union { uint32_t u[4]; bf16x8 v; } cvt;
          cvt.u[0] = sel ? a00 : a10;
          cvt.u[1] = sel ? a01 : a11;
          cvt.u[2] = sel ? b00 : b10;
          cvt.u[3] = sel ? b01 : b11;
          B3[nt] = cvt.v;
        }
        // phase 3: kac += W3-frag @ B3 over this wave's hid2 k-slice
        const int ks3 = wave * 4 + pass * 2 + kt;
#pragma unroll
        for (int m3 = 0; m3 < 6; ++m3) {
          bf16x8 a3 = *(const bf16x8*)(W3f + (size_t)(ks3 * 6 + m3) * 512 + lane * 8);
#pragma unroll
          for (int nt = 0; nt < 4; ++nt)
            kac[m3][nt] = __builtin_amdgcn_mfma_f32_16x16x32_bf16(a3, B3[nt], kac[m3][nt], 0, 0, 0);
        }
      }
    }
    __syncthreads();   // all h1s reads done; region becomes slot buffer

    // write per-wave bf16 partials: slots[wave][n][m] (swizzled granules)
#pragma unroll
    for (int m3 = 0; m3 < 6; ++m3) {
      const int m0 = m3 * 16 + q * 4;
#pragma unroll
      for (int nt = 0; nt < 4; ++nt) {
        const int bn = nt * 16 + l16;
        uint64_t pk = (uint64_t)pk2(kac[m3][nt][0], kac[m3][nt][1])
                    | ((uint64_t)pk2(kac[m3][nt][2], kac[m3][nt][3]) << 32);
        *(uint64_t*)(h1s + wave * 8192 + bn * 128 + (((m0 >> 3) ^ (bn & 7)) << 3) + (m0 & 4)) = pk;
      }
    }
    __syncthreads();

    // ===================== reduce + RK combine (NT strips) =================
    float wk, cc;
    if      (stage == 0) { wk = hh / 6.0f; cc = hh / 2.0f; }
    else if (stage == 1) { wk = hh / 3.0f; cc = hh / 2.0f; }
    else if (stage == 2) { wk = hh / 3.0f; cc = hh; }
    else                 { wk = hh / 6.0f; cc = 0.0f; }

#pragma unroll
    for (int rep = 0; rep < 2; ++rep) {
      const int n  = rep * 32 + (tid >> 4);
      const int m0 = (tid & 15) * 8;
      const int gsw = (((m0 >> 3) ^ (n & 7)) << 3);
      if (m0 < CMB) {
        float kt8[8];
#pragma unroll
        for (int e = 0; e < 8; ++e) kt8[e] = b3[m0 + e];
#pragma unroll
        for (int w = 0; w < 8; ++w) {
          bf16x8 v = *(const bf16x8*)(h1s + w * 8192 + n * 128 + gsw);
#pragma unroll
          for (int e = 0; e < 8; ++e) kt8[e] += (float)v[e];
        }
        const int yi = n * CMB + m0;
        f32x4* ysp = (f32x4*)(ys + yi);
        f32x4* kcp = (f32x4*)(kcs + yi);
        f32x4 y0 = __builtin_nontemporal_load(ysp);
        f32x4 y1 = __builtin_nontemporal_load(ysp + 1);
        float a[8];
        if (stage == 3) {
          f32x4 k0 = __builtin_nontemporal_load(kcp);
          f32x4 k1 = __builtin_nontemporal_load(kcp + 1);
#pragma unroll
          for (int e = 0; e < 4; ++e) {
            y0[e] += k0[e] + wk * kt8[e];
            y1[e] += k1[e] + wk * kt8[4 + e];
            a[e] = y0[e]; a[4 + e] = y1[e];
          }
          __builtin_nontemporal_store(y0, ysp);
          __builtin_nontemporal_store(y1, ysp + 1);
        } else {
          f32x4 k0, k1;
          if (stage == 0) { k0 = z4; k1 = z4; }
          else { k0 = __builtin_nontemporal_load(kcp); k1 = __builtin_nontemporal_load(kcp + 1); }
#pragma unroll
          for (int e = 0; e < 4; ++e) {
            k0[e] += wk * kt8[e];
            k1[e] += wk * kt8[4 + e];
            a[e]     = y0[e] + cc * kt8[e];
            a[4 + e] = y1[e] + cc * kt8[4 + e];
          }
          __builtin_nontemporal_store(k0, kcp);
          __builtin_nontemporal_store(k1, kcp + 1);
        }
        uint16_t av[8];
#pragma unroll
        for (int e = 0; e < 8; ++e) av[e] = f2bf(a[e]);
        *(uint64_t*)(ains + n * 128 + gsw)     = *(const uint64_t*)&av[0];
        *(uint64_t*)(ains + n * 128 + gsw + 4) = *(const uint64_t*)&av[4];
      } else {
        uint16_t av[8];
#pragma unroll
        for (int e = 0; e < 8; ++e) av[e] = (m0 + e == CMB) ? (uint16_t)0x3F80 : (uint16_t)0;
        *(uint64_t*)(ains + n * 128 + gsw)     = *(const uint64_t*)&av[0];
        *(uint64_t*)(ains + n * 128 + gsw + 4) = *(const uint64_t*)&av[4];
      }
    }
    __syncthreads();
  }

  // ---------------- output: action = y[:,64:96], std = exp(log_std) --------
  for (int e = tid; e < 64 * 32; e += 512) {
    int n = e >> 5, c = e & 31;
    int grow = blk * 64 + n;
    out[(size_t)grow * OUT_D + c] = __builtin_nontemporal_load(&ys[n * CMB + IN_D + c]);
    out[(size_t)Bsz * OUT_D + (size_t)grow * OUT_D + c] = expf(lstd[c]);
  }
}

extern "C" void kernel_launch(void* const* d_in, const int* in_sizes, int n_in,
                              void* d_out, int out_size, void* d_ws, size_t ws_size,
                              hipStream_t stream) {
  const float* x    = (const float*)d_in[0];
  const float* z    = (const float*)d_in[1];
  const float* W1   = (const float*)d_in[2];
  const float* b1   = (const float*)d_in[3];
  const float* W2   = (const float*)d_in[4];
  const float* b2   = (const float*)d_in[5];
  const float* W3   = (const float*)d_in[6];
  const float* b3   = (const float*)d_in[7];
  const float* lstd = (const float*)d_in[8];
  float* out = (float*)d_out;
  (void)in_sizes; (void)n_in; (void)out_size; (void)ws_size;

  char* p = (char*)d_ws;
  auto alloc = [&](size_t bytes) {
    char* r = p;
    p += (bytes + 255) & ~(size_t)255;
    return r;
  };
  uint16_t* W1f = (uint16_t*)alloc((size_t)64 * 4  * 512 * 2);  // 256 KB
  uint16_t* W2f = (uint16_t*)alloc((size_t)64 * 32 * 512 * 2);  // 2 MB
  uint16_t* W3f = (uint16_t*)alloc((size_t)6  * 32 * 512 * 2);  // 192 KB
  char*     strips = alloc((size_t)256 * 49152);                // 12 MB

  // W1: b1 folded at k==96, grouped-4. W2: grouped-4. W3: ks-major.
  {
    int tot1 = 64 * 4 * 512;
    pack_w<<<(tot1 + 255) / 256, 256, 0, stream>>>(W1, b1, W1f, CMB, HID, 4, 64, 0, tot1);
    int tot2 = 64 * 32 * 512;
    pack_w<<<(tot2 + 255) / 256, 256, 0, stream>>>(W2, nullptr, W2f, HID, HID, 32, 64, 0, tot2);
    int tot3 = 6 * 32 * 512;
    pack_w<<<(tot3 + 255) / 256, 256, 0, stream>>>(W3, nullptr, W3f, HID, CMB, 32, 6, 1, tot3);
  }

  ode_kernel<<<256, 512, 0, stream>>>(x, z, W1f, W2f, W3f, b2, b3, lstd, out, strips);
}